// Round 1
// baseline (1034.851 us; speedup 1.0000x reference)
//
#include <hip/hip_runtime.h>
#include <hip/hip_cooperative_groups.h>

namespace cg = cooperative_groups;

// SST input layer: window partition + per-window drop + flat2win re-indexing.
// Static config from the reference:
//   WIN=12, GRID=468, BATCH=4, SHIFTS=((0,0),(6,6)), MAX_WIN_Y=40,
//   MAX_WIN_PER_SAMPLE=1600 -> window ids in [0, 6400)
//   DROP_INFO: cnt<30 -> lvl0,target30 ; cnt<60 -> lvl1,target60 ;
//              cnt<100000 -> lvl2,target100 ; else lvl-1,target0

#define NWIN 6400
#define SEG_CAP 3072   // per-window LDS segment cap (12 KB); stat max count ~100
#define CBLK 512       // cooperative grid: 2 blocks/CU * 256 CUs
#define CTHR 256

// ======================= cooperative fused pipeline =======================
// Key algebraic facts used:
//  * shift-1 kept set is an index-prefix of window members (rank r kept iff
//    r < target; every smaller-index member has rank < r), so
//    rank-among-final-kept == rank, and keptC1 = min(k, target).
//  * masked shift-1 histogram can be taken at the instant keep0 is decided.

__device__ __forceinline__ void scan6400(const int* __restrict__ cnt,
                                         int* __restrict__ base,
                                         int* __restrict__ lvlW,
                                         int* psum) {
    int t = threadIdx.x;
    int st = t * 25;              // 256 * 25 = 6400
    int s = 0;
    for (int j = 0; j < 25; j++) s += cnt[st + j];
    psum[t] = s;
    __syncthreads();
    if (t == 0) {
        int acc = 0;
        for (int j = 0; j < 256; j++) { int v = psum[j]; psum[j] = acc; acc += v; }
    }
    __syncthreads();
    int acc = psum[t];
    for (int j = 0; j < 25; j++) {
        int w = st + j;
        int c = cnt[w];
        base[w] = acc;
        acc += c;
        lvlW[w] = (c < 30) ? 0 : (c < 60) ? 1 : (c < 100000) ? 2 : -1;
    }
}

__device__ __forceinline__ void conti6400(const int* __restrict__ lvlW,
                                          const int* __restrict__ keptC,
                                          int* __restrict__ conti,
                                          int* pc0, int* pc1, int* pc2) {
    int t = threadIdx.x;
    int st = t * 25;
    int c0 = 0, c1 = 0, c2 = 0;
    for (int j = 0; j < 25; j++) {
        int w = st + j;
        if (keptC[w] > 0) {
            int l = lvlW[w];
            c0 += (l == 0); c1 += (l == 1); c2 += (l == 2);
        }
    }
    pc0[t] = c0; pc1[t] = c1; pc2[t] = c2;
    __syncthreads();
    if (t == 0) {
        int a = 0, b = 0, c = 0;
        for (int j = 0; j < 256; j++) {
            int v0 = pc0[j], v1 = pc1[j], v2 = pc2[j];
            pc0[j] = a; pc1[j] = b; pc2[j] = c;
            a += v0; b += v1; c += v2;
        }
    }
    __syncthreads();
    int a0 = pc0[t], a1 = pc1[t], a2 = pc2[t];
    for (int j = 0; j < 25; j++) {
        int w = st + j;
        int l = lvlW[w];
        conti[w] = (l == 0) ? a0 : (l == 1) ? a1 : (l == 2) ? a2 : 0;
        if (keptC[w] > 0) {
            if (l == 0) a0++; else if (l == 1) a1++; else if (l == 2) a2++;
        }
    }
}

__global__ void __launch_bounds__(CTHR, 2)
k_coop(const int* __restrict__ coors, int n, int* __restrict__ ws,
       float* __restrict__ out) {
    cg::grid_group grid = cg::this_grid();

    int* cnt0   = ws;
    int* cur0   = ws + 6400;
    int* cnt1   = ws + 12800;
    int* cur1   = ws + 19200;
    int* base0  = ws + 25600;
    int* base1  = ws + 32000;
    int* lvlW0  = ws + 38400;
    int* lvlW1  = ws + 44800;
    int* keptC0 = ws + 51200;
    int* keptC1 = ws + 57600;
    int* conti0 = ws + 64000;
    int* conti1 = ws + 70400;
    int* w0a    = ws + 76800;
    int* w1a    = w0a + n;
    int* seg0   = w1a + n;
    int* seg1   = seg0 + n;
    int* keep0  = seg1 + n;
    int* keepF  = keep0 + n;
    int* rk0    = keepF + n;
    int* rk1    = rk0 + n;

    __shared__ int lds[SEG_CAP];
    __shared__ int red[256];
    __shared__ int pcA[256], pcB[256], pcC[256];

    const int tid  = threadIdx.x;
    const int gid0 = blockIdx.x * CTHR + tid;
    const int gs   = gridDim.x * CTHR;

    // ---- P0: zero counters (cnt0,cur0,cnt1,cur1 contiguous) + keepF ----
    for (int i = gid0; i < 4 * NWIN; i += gs) ws[i] = 0;
    for (int i = gid0; i < n; i += gs) keepF[i] = 0;
    grid.sync();

    // ---- P1: per-voxel window ids (both shifts) + shift-0 histogram ----
    const int4* c4 = (const int4*)coors;   // [b, z, y, x]
    for (int i = gid0; i < n; i += gs) {
        int4 c = c4[i];
        int w0 = c.x * 1600 + (c.w / 12) * 40 + (c.z / 12);
        int w1 = c.x * 1600 + ((c.w + 6) / 12) * 40 + ((c.z + 6) / 12);
        w0a[i] = w0; w1a[i] = w1;
        atomicAdd(&cnt0[w0], 1);
    }
    grid.sync();

    // ---- P2: exclusive scan over shift-0 counts + window drop level ----
    if (blockIdx.x == 0) scan6400(cnt0, base0, lvlW0, red);
    grid.sync();

    // ---- P3: scatter voxel indices into shift-0 window segments ----
    for (int i = gid0; i < n; i += gs) {
        int w = w0a[i];
        int p = atomicAdd(&cur0[w], 1);
        seg0[base0[w] + p] = i;
    }
    grid.sync();

    // ---- P4: shift-0 rank/keep + fused masked shift-1 histogram ----
    for (int w = blockIdx.x; w < NWIN; w += gridDim.x) {
        int k = cnt0[w];
        if (k == 0) continue;                    // uniform per block
        int bs = base0[w];
        int target = (k < 30) ? 30 : (k < 60) ? 60 : (k < 100000) ? 100 : 0;
        if (k <= SEG_CAP) {
            for (int j = tid; j < k; j += CTHR) lds[j] = seg0[bs + j];
            __syncthreads();
            for (int e = tid; e < k; e += CTHR) {
                int v = lds[e];
                int r = 0;
                for (int j = 0; j < k; j++) r += (lds[j] < v) ? 1 : 0;
                int kp = (r < target) ? 1 : 0;
                keep0[v] = kp;
                if (kp) atomicAdd(&cnt1[w1a[v]], 1);
            }
            __syncthreads();                     // protect lds reuse
        } else {                                 // statistical never; fallback
            for (int e = tid; e < k; e += CTHR) {
                int v = seg0[bs + e];
                int r = 0;
                for (int j = 0; j < k; j++) r += (seg0[bs + j] < v) ? 1 : 0;
                int kp = (r < target) ? 1 : 0;
                keep0[v] = kp;
                if (kp) atomicAdd(&cnt1[w1a[v]], 1);
            }
        }
    }
    grid.sync();

    // ---- P5: exclusive scan over masked shift-1 counts ----
    if (blockIdx.x == 0) scan6400(cnt1, base1, lvlW1, red);
    grid.sync();

    // ---- P6: scatter keep0 survivors into shift-1 window segments ----
    for (int i = gid0; i < n; i += gs) {
        if (!keep0[i]) continue;
        int w = w1a[i];
        int p = atomicAdd(&cur1[w], 1);
        seg1[base1[w] + p] = i;
    }
    grid.sync();

    // ---- P7: shift-1 rank -> keepF, rk1 (= rank-among-kept), keptC1 ----
    for (int w = blockIdx.x; w < NWIN; w += gridDim.x) {
        int k = cnt1[w];
        int target = (k < 30) ? 30 : (k < 60) ? 60 : (k < 100000) ? 100 : 0;
        if (tid == 0) keptC1[w] = (k < target) ? k : target;
        if (k == 0) continue;
        int bs = base1[w];
        if (k <= SEG_CAP) {
            for (int j = tid; j < k; j += CTHR) lds[j] = seg1[bs + j];
            __syncthreads();
            for (int e = tid; e < k; e += CTHR) {
                int v = lds[e];
                int r = 0;
                for (int j = 0; j < k; j++) r += (lds[j] < v) ? 1 : 0;
                if (r < target) { keepF[v] = 1; rk1[v] = r; }
            }
            __syncthreads();
        } else {
            for (int e = tid; e < k; e += CTHR) {
                int v = seg1[bs + e];
                int r = 0;
                for (int j = 0; j < k; j++) r += (seg1[bs + j] < v) ? 1 : 0;
                if (r < target) { keepF[v] = 1; rk1[v] = r; }
            }
        }
    }
    grid.sync();

    // ---- P8: shift-0 rank among FINAL-kept -> rk0, keptC0 ----
    for (int w = blockIdx.x; w < NWIN; w += gridDim.x) {
        int k = cnt0[w];
        int bs = base0[w];
        int local = 0;
        if (k > 0 && k <= SEG_CAP) {
            for (int j = tid; j < k; j += CTHR) {
                int v = seg0[bs + j];
                lds[j] = v | (keepF[v] << 30);   // pack kept flag (idx < 2^30)
            }
            __syncthreads();
            for (int e = tid; e < k; e += CTHR) {
                int enc = lds[e];
                int kept = enc >> 30;
                local += kept;
                if (kept) {
                    int v = enc & 0x3FFFFFFF;
                    int r = 0;
                    for (int j = 0; j < k; j++) {
                        int ej = lds[j];
                        r += (ej >> 30) & (int)((ej & 0x3FFFFFFF) < v);
                    }
                    rk0[v] = r;
                }
            }
        } else if (k > 0) {
            for (int e = tid; e < k; e += CTHR) {
                int v = seg0[bs + e];
                int f = keepF[v];
                local += f;
                if (f) {
                    int r = 0;
                    for (int j = 0; j < k; j++) {
                        int u = seg0[bs + j];
                        r += (keepF[u] && (u < v)) ? 1 : 0;
                    }
                    rk0[v] = r;
                }
            }
        }
        red[tid] = local;
        __syncthreads();
        if (tid == 0) {
            int s = 0;
            for (int j = 0; j < 256; j++) s += red[j];
            keptC0[w] = s;
        }
        __syncthreads();                         // protect red/lds reuse
    }
    grid.sync();

    // ---- P9: dense window ranks per level (both shifts, concurrent) ----
    if (blockIdx.x == 0)      conti6400(lvlW0, keptC0, conti0, pcA, pcB, pcC);
    else if (blockIdx.x == 1) conti6400(lvlW1, keptC1, conti1, pcA, pcB, pcC);
    grid.sync();

    // ---- P10: per-voxel scalar outputs (7 arrays as float32) ----
    size_t N = (size_t)n;
    float* o = out + N * 128;   // after feat block
    for (int i = gid0; i < n; i += gs) {
        int w0 = w0a[i], w1 = w1a[i];
        int k0 = keep0[i];
        int kf = keepF[i];
        int l0 = lvlW0[w0];
        int l1 = k0 ? lvlW1[w1] : -1;
        int f0 = -1, f1 = -1;
        if (kf) {
            int mt0 = (l0 == 0) ? 30 : (l0 == 1) ? 60 : 100;
            int mt1 = (l1 == 0) ? 30 : (l1 == 1) ? 60 : 100;
            f0 = conti0[w0] * mt0 + rk0[i];
            f1 = conti1[w1] * mt1 + rk1[i];
        }
        o[i]         = (float)kf;   // keep
        o[N + i]     = (float)l0;   // lvl0
        o[2 * N + i] = (float)l1;   // lvl1
        o[3 * N + i] = (float)w0;   // bwi0
        o[4 * N + i] = (float)w1;   // bwi1
        o[5 * N + i] = (float)f0;   // f2w0
        o[6 * N + i] = (float)f1;   // f2w1
    }
}

// ---- masked feature copy (HBM-bound): float4-vectorized, wide grid ----
__global__ void k_feat(const float4* __restrict__ in, const int* __restrict__ keepF,
                       float4* __restrict__ out, int n) {
    int gid = blockIdx.x * blockDim.x + threadIdx.x;
    int total = n * 32;            // 128 floats = 32 float4 per row
    if (gid >= total) return;
    int row = gid >> 5;
    float4 v = in[gid];
    if (!keepF[row]) { v.x = 0.f; v.y = 0.f; v.z = 0.f; v.w = 0.f; }
    out[gid] = v;
}

// ======================= fallback (non-cooperative) path =======================

__global__ void k_zero(int* __restrict__ hdr, int* __restrict__ keepF, int n) {
    int i = blockIdx.x * blockDim.x + threadIdx.x;
    if (i < 4 * NWIN) hdr[i] = 0;
    if (i < n) keepF[i] = 0;
}

__global__ void k_windows(const int* __restrict__ coors, int n,
                          int* __restrict__ w0a, int* __restrict__ w1a,
                          int* __restrict__ cnt0) {
    int i = blockIdx.x * blockDim.x + threadIdx.x;
    if (i >= n) return;
    int b = coors[4 * i];
    int y = coors[4 * i + 2];
    int x = coors[4 * i + 3];
    int w0 = b * 1600 + (x / 12) * 40 + (y / 12);
    int w1 = b * 1600 + ((x + 6) / 12) * 40 + ((y + 6) / 12);
    w0a[i] = w0;
    w1a[i] = w1;
    atomicAdd(&cnt0[w0], 1);
}

__global__ void k_scan(const int* __restrict__ cnt, int* __restrict__ base,
                       int* __restrict__ lvlW) {
    __shared__ int psum[256];
    scan6400(cnt, base, lvlW, psum);
}

__global__ void k_count_masked(const int* __restrict__ wa, const int* __restrict__ mask,
                               int n, int* __restrict__ cnt) {
    int i = blockIdx.x * blockDim.x + threadIdx.x;
    if (i >= n) return;
    if (!mask[i]) return;
    atomicAdd(&cnt[wa[i]], 1);
}

__global__ void k_scatter(const int* __restrict__ wa, const int* __restrict__ mask, int n,
                          const int* __restrict__ base, int* __restrict__ cur,
                          int* __restrict__ seg) {
    int i = blockIdx.x * blockDim.x + threadIdx.x;
    if (i >= n) return;
    if (mask && !mask[i]) return;
    int w = wa[i];
    int p = atomicAdd(&cur[w], 1);
    seg[base[w] + p] = i;
}

__global__ void k_rankkeep(const int* __restrict__ cnt, const int* __restrict__ base,
                           const int* __restrict__ seg, int* __restrict__ keepOut) {
    int w = blockIdx.x;
    int k = cnt[w];
    if (k == 0) return;
    int bs = base[w];
    int target;
    if (k < 30) target = 30;
    else if (k < 60) target = 60;
    else if (k < 100000) target = 100;
    else target = 0;
    __shared__ int lds[SEG_CAP];
    if (k <= SEG_CAP) {
        for (int j = threadIdx.x; j < k; j += blockDim.x) lds[j] = seg[bs + j];
        __syncthreads();
        for (int e = threadIdx.x; e < k; e += blockDim.x) {
            int v = lds[e];
            int r = 0;
            for (int j = 0; j < k; j++) r += (lds[j] < v) ? 1 : 0;
            keepOut[v] = (r < target) ? 1 : 0;
        }
    } else {
        for (int e = threadIdx.x; e < k; e += blockDim.x) {
            int v = seg[bs + e];
            int r = 0;
            for (int j = 0; j < k; j++) r += (seg[bs + j] < v) ? 1 : 0;
            keepOut[v] = (r < target) ? 1 : 0;
        }
    }
}

__global__ void k_rankkept(const int* __restrict__ cnt, const int* __restrict__ base,
                           const int* __restrict__ seg, const int* __restrict__ keepF,
                           int* __restrict__ rk, int* __restrict__ keptC) {
    int w = blockIdx.x;
    int k = cnt[w];
    __shared__ int lds[SEG_CAP];
    __shared__ int red[64];
    int local = 0;
    if (k > 0) {
        int bs = base[w];
        if (k <= SEG_CAP) {
            for (int j = threadIdx.x; j < k; j += blockDim.x) {
                int v = seg[bs + j];
                lds[j] = v | (keepF[v] << 30);
            }
            __syncthreads();
            for (int e = threadIdx.x; e < k; e += blockDim.x) {
                int enc = lds[e];
                int kept = enc >> 30;
                local += kept;
                if (!kept) continue;
                int v = enc & 0x3FFFFFFF;
                int r = 0;
                for (int j = 0; j < k; j++) {
                    int ej = lds[j];
                    r += (ej >> 30) & (int)((ej & 0x3FFFFFFF) < v);
                }
                rk[v] = r;
            }
        } else {
            for (int e = threadIdx.x; e < k; e += blockDim.x) {
                int v = seg[bs + e];
                int f = keepF[v];
                local += f;
                if (!f) continue;
                int r = 0;
                for (int j = 0; j < k; j++) {
                    int u = seg[bs + j];
                    r += (keepF[u] && (u < v)) ? 1 : 0;
                }
                rk[v] = r;
            }
        }
    }
    red[threadIdx.x] = local;
    __syncthreads();
    if (threadIdx.x == 0) {
        int s = 0;
        for (int j = 0; j < 64; j++) s += red[j];
        keptC[w] = s;
    }
}

__global__ void k_conti(const int* __restrict__ lvlW, const int* __restrict__ keptC,
                        int* __restrict__ conti) {
    __shared__ int pc0[256], pc1[256], pc2[256];
    conti6400(lvlW, keptC, conti, pc0, pc1, pc2);
}

__global__ void k_final(int n, const int* __restrict__ w0a, const int* __restrict__ w1a,
                        const int* __restrict__ keep0, const int* __restrict__ keepF,
                        const int* __restrict__ lvlW0, const int* __restrict__ lvlW1,
                        const int* __restrict__ conti0, const int* __restrict__ conti1,
                        const int* __restrict__ rk0, const int* __restrict__ rk1,
                        float* __restrict__ out) {
    int i = blockIdx.x * blockDim.x + threadIdx.x;
    if (i >= n) return;
    size_t N = (size_t)n;
    float* o = out + N * 128;
    int w0 = w0a[i], w1 = w1a[i];
    int k0 = keep0[i];
    int kf = keepF[i];
    int l0 = lvlW0[w0];
    int l1 = k0 ? lvlW1[w1] : -1;
    int f0 = -1, f1 = -1;
    if (kf) {
        int mt0 = (l0 == 0) ? 30 : (l0 == 1) ? 60 : 100;
        int mt1 = (l1 == 0) ? 30 : (l1 == 1) ? 60 : 100;
        f0 = conti0[w0] * mt0 + rk0[i];
        f1 = conti1[w1] * mt1 + rk1[i];
    }
    o[i]         = (float)kf;
    o[N + i]     = (float)l0;
    o[2 * N + i] = (float)l1;
    o[3 * N + i] = (float)w0;
    o[4 * N + i] = (float)w1;
    o[5 * N + i] = (float)f0;
    o[6 * N + i] = (float)f1;
}

extern "C" void kernel_launch(void* const* d_in, const int* in_sizes, int n_in,
                              void* d_out, int out_size, void* d_ws, size_t ws_size,
                              hipStream_t stream) {
    (void)n_in; (void)out_size; (void)ws_size;
    const float* feat = (const float*)d_in[0];
    const int* coors  = (const int*)d_in[1];
    int n = in_sizes[1] / 4;           // coors is [N,4]
    float* out = (float*)d_out;
    int* ws = (int*)d_ws;

    // workspace layout (ints), identical for both paths
    int* cnt0   = ws;
    int* cur0   = ws + 6400;
    int* cnt1   = ws + 12800;
    int* cur1   = ws + 19200;
    int* base0  = ws + 25600;
    int* base1  = ws + 32000;
    int* lvlW0  = ws + 38400;
    int* lvlW1  = ws + 44800;
    int* keptC0 = ws + 51200;
    int* keptC1 = ws + 57600;
    int* conti0 = ws + 64000;
    int* conti1 = ws + 70400;
    int* w0a    = ws + 76800;
    int* w1a    = w0a + n;
    int* seg0   = w1a + n;
    int* seg1   = seg0 + n;
    int* keep0  = seg1 + n;
    int* keepF  = keep0 + n;
    int* rk0    = keepF + n;
    int* rk1    = rk0 + n;

    void* kargs[4] = { (void*)&coors, (void*)&n, (void*)&ws, (void*)&out };
    hipError_t err = hipLaunchCooperativeKernel((const void*)k_coop,
                                                dim3(CBLK), dim3(CTHR),
                                                kargs, 0, stream);
    if (err != hipSuccess) {
        // fallback: original multi-kernel pipeline
        int nb = (n + 255) / 256;
        int zmax = (n > 4 * NWIN) ? n : 4 * NWIN;
        int zb = (zmax + 255) / 256;
        k_zero<<<zb, 256, 0, stream>>>(cnt0, keepF, n);
        k_windows<<<nb, 256, 0, stream>>>(coors, n, w0a, w1a, cnt0);
        k_scan<<<1, 256, 0, stream>>>(cnt0, base0, lvlW0);
        k_scatter<<<nb, 256, 0, stream>>>(w0a, (const int*)nullptr, n, base0, cur0, seg0);
        k_rankkeep<<<NWIN, 64, 0, stream>>>(cnt0, base0, seg0, keep0);
        k_count_masked<<<nb, 256, 0, stream>>>(w1a, keep0, n, cnt1);
        k_scan<<<1, 256, 0, stream>>>(cnt1, base1, lvlW1);
        k_scatter<<<nb, 256, 0, stream>>>(w1a, keep0, n, base1, cur1, seg1);
        k_rankkeep<<<NWIN, 64, 0, stream>>>(cnt1, base1, seg1, keepF);
        k_rankkept<<<NWIN, 64, 0, stream>>>(cnt0, base0, seg0, keepF, rk0, keptC0);
        k_rankkept<<<NWIN, 64, 0, stream>>>(cnt1, base1, seg1, keepF, rk1, keptC1);
        k_conti<<<1, 256, 0, stream>>>(lvlW0, keptC0, conti0);
        k_conti<<<1, 256, 0, stream>>>(lvlW1, keptC1, conti1);
        k_final<<<nb, 256, 0, stream>>>(n, w0a, w1a, keep0, keepF, lvlW0, lvlW1,
                                        conti0, conti1, rk0, rk1, out);
    }
    int fb = (n * 32 + 255) / 256;
    k_feat<<<fb, 256, 0, stream>>>((const float4*)feat, keepF, (float4*)out, n);
}

// Round 2
// 396.073 us; speedup vs baseline: 2.6128x; 2.6128x over previous
//
#include <hip/hip_runtime.h>

// SST input layer: window partition + per-window drop + flat2win re-indexing.
// Static config from the reference:
//   WIN=12, GRID=468, BATCH=4, SHIFTS=((0,0),(6,6)), MAX_WIN_Y=40,
//   MAX_WIN_PER_SAMPLE=1600 -> window ids in [0, 6400)
//   DROP_INFO: cnt<30 -> lvl0,target30 ; cnt<60 -> lvl1,target60 ;
//              cnt<100000 -> lvl2,target100 ; else lvl-1,target0
//
// Structure (7 stream-ordered dispatches, no grid.sync — R1 showed coop
// grid.sync costs ~75us/sync on gfx950 due to cross-XCD coherence):
//   K0 zero      : cnt0,cnt1,keptC0 (19200 ints)
//   K1 winscat   : window ids + scatter into fixed-CAP shift-0 segments
//   K2 rank0     : wave/window shfl rank -> keep0, fused shift-1 hist+scatter
//   K3 rank1     : wave/window shfl rank -> keepF, rk1, keptC1 (closed form),
//                  keptC0 via atomics   [rank-among-kept == rank: prefix property]
//   K4 rank0kept : wave/window shfl rank among final-kept -> rk0
//   K5 conti2    : dense window rank per level, both shifts (2 blocks)
//   K6 finalfeat : per-voxel scalar outputs + masked float4 feature copy
//
// Key verified facts (R1 coop run passed with absmax=0):
//   * shift-1 kept set is an index-prefix of window members => rank-among-kept
//     == rank and keptC1 = min(k, target).
//   * masked shift-1 histogram can be taken when keep0 is decided.
// Garbage-safety: keepF is only written for keep0-survivors; all consumers
// use (keep0 && keepF), so stale keepF from prior launches is masked.

#define NWIN 6400
#define CAP 128   // per-window segment capacity; stat max count ~80 (11 sigma)

__device__ __forceinline__ int targ_of(int k) {
    return (k < 30) ? 30 : (k < 60) ? 60 : (k < 100000) ? 100 : 0;
}
__device__ __forceinline__ int lvl_of(int k) {
    return (k < 30) ? 0 : (k < 60) ? 1 : (k < 100000) ? 2 : -1;
}

// ---- K0: zero cnt0, cnt1, keptC0 (contiguous 3*6400 ints) ----
__global__ void k_zero(int* __restrict__ z) {
    int i = blockIdx.x * 256 + threadIdx.x;
    if (i < 3 * NWIN) z[i] = 0;
}

// ---- K1: window ids for both shifts + scatter into shift-0 segments ----
__global__ void __launch_bounds__(256) k_winscat(
    const int4* __restrict__ c4, int n,
    int* __restrict__ w0a, int* __restrict__ w1a,
    int* __restrict__ cnt0, int* __restrict__ seg0) {
    int i = blockIdx.x * 256 + threadIdx.x;
    if (i >= n) return;
    int4 c = c4[i];                                  // [b, z, y, x]
    int w0 = c.x * 1600 + (c.w / 12) * 40 + (c.z / 12);
    int w1 = c.x * 1600 + ((c.w + 6) / 12) * 40 + ((c.z + 6) / 12);
    w0a[i] = w0;
    w1a[i] = w1;
    int p = atomicAdd(&cnt0[w0], 1);
    if (p < CAP) seg0[w0 * CAP + p] = i;             // overflow -> serial path
}

// ---- K2: shift-0 rank/keep (wave per window) + fused shift-1 hist+scatter ----
__global__ void __launch_bounds__(256) k_rank0(
    const int* __restrict__ cnt0, const int* __restrict__ seg0,
    const int* __restrict__ w0a, const int* __restrict__ w1a, int n,
    int* __restrict__ keep0, int* __restrict__ cnt1, int* __restrict__ seg1) {
    int w = blockIdx.x * 4 + (threadIdx.x >> 6);
    int lane = threadIdx.x & 63;
    int k = cnt0[w];
    if (k == 0) return;
    int target = targ_of(k);
    const int* s = seg0 + w * CAP;
    if (k <= 64) {
        int v = (lane < k) ? s[lane] : 0x7FFFFFFF;
        int r = 0;
        for (int j = 0; j < k; j++) { int b = __shfl(v, j, 64); r += (b < v) ? 1 : 0; }
        if (lane < k) {
            int kp = (r < target) ? 1 : 0;
            keep0[v] = kp;
            if (kp) {
                int w1 = w1a[v];
                int p = atomicAdd(&cnt1[w1], 1);
                if (p < CAP) seg1[w1 * CAP + p] = v;
            }
        }
    } else if (k <= CAP) {
        int k2 = k - 64;
        int v0 = s[lane];
        int v1 = (lane < k2) ? s[64 + lane] : 0x7FFFFFFF;
        int r0 = 0, r1 = 0;
        for (int j = 0; j < 64; j++) { int b = __shfl(v0, j, 64); r0 += (b < v0); r1 += (b < v1); }
        for (int j = 0; j < k2; j++) { int b = __shfl(v1, j, 64); r0 += (b < v0); r1 += (b < v1); }
        {
            int kp = (r0 < target) ? 1 : 0;
            keep0[v0] = kp;
            if (kp) { int w1 = w1a[v0]; int p = atomicAdd(&cnt1[w1], 1); if (p < CAP) seg1[w1 * CAP + p] = v0; }
        }
        if (lane < k2) {
            int kp = (r1 < target) ? 1 : 0;
            keep0[v1] = kp;
            if (kp) { int w1 = w1a[v1]; int p = atomicAdd(&cnt1[w1], 1); if (p < CAP) seg1[w1 * CAP + p] = v1; }
        }
    } else {
        // correctness fallback (statistically never): serial in-order scan
        if (lane == 0) {
            int c = 0;
            for (int i = 0; i < n; i++) {
                if (w0a[i] == w) {
                    int kp = (c < target) ? 1 : 0;
                    keep0[i] = kp;
                    if (kp) { int w1 = w1a[i]; int p = atomicAdd(&cnt1[w1], 1); if (p < CAP) seg1[w1 * CAP + p] = i; }
                    c++;
                }
            }
        }
    }
}

// ---- K3: shift-1 rank -> keepF, rk1, keptC1 (closed form), keptC0 atomics ----
__global__ void __launch_bounds__(256) k_rank1(
    const int* __restrict__ cnt1, const int* __restrict__ seg1,
    const int* __restrict__ w0a, const int* __restrict__ w1a,
    const int* __restrict__ keep0, int n,
    int* __restrict__ keepF, int* __restrict__ rk1,
    int* __restrict__ keptC1, int* __restrict__ keptC0) {
    int w = blockIdx.x * 4 + (threadIdx.x >> 6);
    int lane = threadIdx.x & 63;
    int k = cnt1[w];
    int target = targ_of(k);
    if (lane == 0) keptC1[w] = (k < target) ? k : target;   // prefix property
    if (k == 0) return;
    const int* s = seg1 + w * CAP;
    if (k <= 64) {
        int v = (lane < k) ? s[lane] : 0x7FFFFFFF;
        int r = 0;
        for (int j = 0; j < k; j++) { int b = __shfl(v, j, 64); r += (b < v) ? 1 : 0; }
        if (lane < k) {
            int kp = (r < target) ? 1 : 0;
            keepF[v] = kp;
            if (kp) { rk1[v] = r; atomicAdd(&keptC0[w0a[v]], 1); }
        }
    } else if (k <= CAP) {
        int k2 = k - 64;
        int v0 = s[lane];
        int v1 = (lane < k2) ? s[64 + lane] : 0x7FFFFFFF;
        int r0 = 0, r1 = 0;
        for (int j = 0; j < 64; j++) { int b = __shfl(v0, j, 64); r0 += (b < v0); r1 += (b < v1); }
        for (int j = 0; j < k2; j++) { int b = __shfl(v1, j, 64); r0 += (b < v0); r1 += (b < v1); }
        {
            int kp = (r0 < target) ? 1 : 0;
            keepF[v0] = kp;
            if (kp) { rk1[v0] = r0; atomicAdd(&keptC0[w0a[v0]], 1); }
        }
        if (lane < k2) {
            int kp = (r1 < target) ? 1 : 0;
            keepF[v1] = kp;
            if (kp) { rk1[v1] = r1; atomicAdd(&keptC0[w0a[v1]], 1); }
        }
    } else {
        if (lane == 0) {
            int c = 0;
            for (int i = 0; i < n; i++) {
                if (w1a[i] == w && keep0[i]) {
                    int kp = (c < target) ? 1 : 0;
                    keepF[i] = kp;
                    if (kp) { rk1[i] = c; atomicAdd(&keptC0[w0a[i]], 1); }
                    c++;
                }
            }
        }
    }
}

// ---- K4: shift-0 rank among FINAL-kept -> rk0 ----
__global__ void __launch_bounds__(256) k_rank0kept(
    const int* __restrict__ cnt0, const int* __restrict__ seg0,
    const int* __restrict__ keep0, const int* __restrict__ keepF,
    const int* __restrict__ w0a, int n, int* __restrict__ rk0) {
    int w = blockIdx.x * 4 + (threadIdx.x >> 6);
    int lane = threadIdx.x & 63;
    int k = cnt0[w];
    if (k == 0) return;
    const int* s = seg0 + w * CAP;
    if (k <= 64) {
        int v = 0x3FFFFFFF, f = 0;
        if (lane < k) { v = s[lane]; f = (keep0[v] && keepF[v]) ? 1 : 0; }
        int enc = v | (f << 30);                      // idx < 2^30
        int r = 0;
        for (int j = 0; j < k; j++) {
            int b = __shfl(enc, j, 64);
            r += ((b >> 30) & 1) & (int)((b & 0x3FFFFFFF) < v);
        }
        if (f) rk0[v] = r;
    } else if (k <= CAP) {
        int k2 = k - 64;
        int v0 = s[lane];
        int f0 = (keep0[v0] && keepF[v0]) ? 1 : 0;
        int v1 = 0x3FFFFFFF, f1 = 0;
        if (lane < k2) { v1 = s[64 + lane]; f1 = (keep0[v1] && keepF[v1]) ? 1 : 0; }
        int e0 = v0 | (f0 << 30), e1 = v1 | (f1 << 30);
        int r0 = 0, r1 = 0;
        for (int j = 0; j < 64; j++) {
            int b = __shfl(e0, j, 64);
            int bf = (b >> 30) & 1, bv = b & 0x3FFFFFFF;
            r0 += bf & (int)(bv < v0);
            r1 += bf & (int)(bv < v1);
        }
        for (int j = 0; j < k2; j++) {
            int b = __shfl(e1, j, 64);
            int bf = (b >> 30) & 1, bv = b & 0x3FFFFFFF;
            r0 += bf & (int)(bv < v0);
            r1 += bf & (int)(bv < v1);
        }
        if (f0) rk0[v0] = r0;
        if (f1) rk0[v1] = r1;
    } else {
        if (lane == 0) {
            int c = 0;
            for (int i = 0; i < n; i++) {
                if (w0a[i] == w && keep0[i] && keepF[i]) { rk0[i] = c; c++; }
            }
        }
    }
}

// ---- K5: dense window rank per drop level, both shifts (2 blocks) ----
__global__ void k_conti2(
    const int* __restrict__ cnt0, const int* __restrict__ keptC0, int* __restrict__ conti0,
    const int* __restrict__ cnt1, const int* __restrict__ keptC1, int* __restrict__ conti1) {
    __shared__ int pc0[256], pc1[256], pc2[256];
    const int* cnt   = blockIdx.x ? cnt1 : cnt0;
    const int* keptC = blockIdx.x ? keptC1 : keptC0;
    int* conti       = blockIdx.x ? conti1 : conti0;
    int t = threadIdx.x;
    int st = t * 25;                                  // 256 * 25 = 6400
    int c0 = 0, c1 = 0, c2 = 0;
    for (int j = 0; j < 25; j++) {
        int w = st + j;
        if (keptC[w] > 0) {
            int l = lvl_of(cnt[w]);
            c0 += (l == 0); c1 += (l == 1); c2 += (l == 2);
        }
    }
    pc0[t] = c0; pc1[t] = c1; pc2[t] = c2;
    __syncthreads();
    if (t == 0) {
        int a = 0, b = 0, c = 0;
        for (int j = 0; j < 256; j++) {
            int v0 = pc0[j], v1 = pc1[j], v2 = pc2[j];
            pc0[j] = a; pc1[j] = b; pc2[j] = c;
            a += v0; b += v1; c += v2;
        }
    }
    __syncthreads();
    int a0 = pc0[t], a1 = pc1[t], a2 = pc2[t];
    for (int j = 0; j < 25; j++) {
        int w = st + j;
        int l = lvl_of(cnt[w]);
        conti[w] = (l == 0) ? a0 : (l == 1) ? a1 : (l == 2) ? a2 : 0;
        if (keptC[w] > 0) {
            if (l == 0) a0++; else if (l == 1) a1++; else if (l == 2) a2++;
        }
    }
}

// ---- K6: per-voxel scalar outputs + masked feature copy (block-split) ----
__global__ void __launch_bounds__(256) k_finalfeat(
    int n, const int* __restrict__ w0a, const int* __restrict__ w1a,
    const int* __restrict__ keep0, const int* __restrict__ keepF,
    const int* __restrict__ cnt0, const int* __restrict__ cnt1,
    const int* __restrict__ conti0, const int* __restrict__ conti1,
    const int* __restrict__ rk0, const int* __restrict__ rk1,
    const float4* __restrict__ feat, float* __restrict__ out, int nbScalar) {
    if ((int)blockIdx.x < nbScalar) {
        int i = blockIdx.x * 256 + threadIdx.x;
        if (i >= n) return;
        size_t N = (size_t)n;
        float* o = out + N * 128;                     // after feat block
        int w0 = w0a[i], w1 = w1a[i];
        int k0 = keep0[i];
        int kf = (k0 && keepF[i]) ? 1 : 0;
        int l0 = lvl_of(cnt0[w0]);
        int l1 = k0 ? lvl_of(cnt1[w1]) : -1;
        int f0 = -1, f1 = -1;
        if (kf) {
            int mt0 = (l0 == 0) ? 30 : (l0 == 1) ? 60 : 100;
            int mt1 = (l1 == 0) ? 30 : (l1 == 1) ? 60 : 100;
            f0 = conti0[w0] * mt0 + rk0[i];
            f1 = conti1[w1] * mt1 + rk1[i];
        }
        o[i]         = (float)kf;   // keep
        o[N + i]     = (float)l0;   // lvl0
        o[2 * N + i] = (float)l1;   // lvl1
        o[3 * N + i] = (float)w0;   // bwi0
        o[4 * N + i] = (float)w1;   // bwi1
        o[5 * N + i] = (float)f0;   // f2w0
        o[6 * N + i] = (float)f1;   // f2w1
    } else {
        int gid = (blockIdx.x - nbScalar) * 256 + threadIdx.x;
        int total = n * 32;                           // 128 floats = 32 float4/row
        if (gid >= total) return;
        int row = gid >> 5;
        float4 v = feat[gid];
        if (!(keep0[row] && keepF[row])) { v.x = 0.f; v.y = 0.f; v.z = 0.f; v.w = 0.f; }
        ((float4*)out)[gid] = v;
    }
}

extern "C" void kernel_launch(void* const* d_in, const int* in_sizes, int n_in,
                              void* d_out, int out_size, void* d_ws, size_t ws_size,
                              hipStream_t stream) {
    (void)n_in; (void)out_size; (void)ws_size;
    const float* feat = (const float*)d_in[0];
    const int* coors  = (const int*)d_in[1];
    int n = in_sizes[1] / 4;           // coors is [N,4]
    float* out = (float*)d_out;
    int* ws = (int*)d_ws;

    // workspace layout (ints): 38400 + 6n + 2*NWIN*CAP ~= 13.9 MB at N=300000
    int* cnt0   = ws;                  // zeroed
    int* cnt1   = ws + 6400;           // zeroed
    int* keptC0 = ws + 12800;          // zeroed
    int* keptC1 = ws + 19200;
    int* conti0 = ws + 25600;
    int* conti1 = ws + 32000;
    int* w0a    = ws + 38400;
    int* w1a    = w0a + n;
    int* keep0  = w1a + n;
    int* keepF  = keep0 + n;
    int* rk0    = keepF + n;
    int* rk1    = rk0 + n;
    int* seg0   = rk1 + n;
    int* seg1   = seg0 + NWIN * CAP;

    int nb = (n + 255) / 256;
    int fb = (n * 32 + 255) / 256;

    k_zero<<<(3 * NWIN + 255) / 256, 256, 0, stream>>>(cnt0);
    k_winscat<<<nb, 256, 0, stream>>>((const int4*)coors, n, w0a, w1a, cnt0, seg0);
    k_rank0<<<NWIN / 4, 256, 0, stream>>>(cnt0, seg0, w0a, w1a, n, keep0, cnt1, seg1);
    k_rank1<<<NWIN / 4, 256, 0, stream>>>(cnt1, seg1, w0a, w1a, keep0, n,
                                          keepF, rk1, keptC1, keptC0);
    k_rank0kept<<<NWIN / 4, 256, 0, stream>>>(cnt0, seg0, keep0, keepF, w0a, n, rk0);
    k_conti2<<<2, 256, 0, stream>>>(cnt0, keptC0, conti0, cnt1, keptC1, conti1);
    k_finalfeat<<<nb + fb, 256, 0, stream>>>(n, w0a, w1a, keep0, keepF, cnt0, cnt1,
                                             conti0, conti1, rk0, rk1,
                                             (const float4*)feat, out, nb);
}

// Round 3
// 390.157 us; speedup vs baseline: 2.6524x; 1.0152x over previous
//
#include <hip/hip_runtime.h>

// SST input layer: window partition + per-window drop + flat2win re-indexing.
// Static config from the reference:
//   WIN=12, GRID=468, BATCH=4, SHIFTS=((0,0),(6,6)), MAX_WIN_Y=40,
//   MAX_WIN_PER_SAMPLE=1600 -> window ids in [0, 6400)
//   DROP_INFO: cnt<30 -> lvl0,target30 ; cnt<60 -> lvl1,target60 ;
//              cnt<100000 -> lvl2,target100 ; else lvl-1,target0
//
// Structure (6 stream-ordered dispatches; R1 showed coop grid.sync costs
// ~75us/sync on gfx950, so fusion is done by removing sync points):
//   K0 zero     : cnt0,cnt1,keptC0,dropCnt
//   K1 winscat  : window ids + scatter into fixed-CAP shift-0 segments
//   K2 rank0    : wave/window shfl rank -> keep0, rk0 (optimistic),
//                 fused shift-1 hist+scatter
//   K3 rank1    : wave/window shfl rank -> keepF, rk1, keptC1 (closed form),
//                 keptC0 via atomics, droplist of shift-1-dropped survivors
//   K4 fix      : blocks 0-1: dense window rank per level (conti, both
//                 shifts); blocks 2+: sparse rk0 decrement from droplist
//                 (statistically empty: drops need window count > 100 at
//                 mean 49, sigma 7)
//   K5 finalfeat: per-voxel scalar outputs + masked float4 feature copy
//
// Verified facts (R1/R2 runs passed, absmax=0):
//   * keep0 kept set within a shift-0 window is an index-prefix of members
//     => rank-among-keep0 == rank-among-all (r).
//   * shift-1 kept set is an index-prefix of survivors => rank-among-kept
//     == rank and keptC1 = min(k, target).
//   * rk0 = r - #{smaller-index keep0-members dropped by shift-1}
//     (the droplist fixup).
// Garbage-safety: keepF is written for every keep0-survivor (both kept and
// dropped); all consumers gate with (keep0 && keepF).

#define NWIN 6400
#define CAP 128   // per-window segment capacity; stat max count ~80 (11 sigma)

__device__ __forceinline__ int targ_of(int k) {
    return (k < 30) ? 30 : (k < 60) ? 60 : (k < 100000) ? 100 : 0;
}
__device__ __forceinline__ int lvl_of(int k) {
    return (k < 30) ? 0 : (k < 60) ? 1 : (k < 100000) ? 2 : -1;
}

// ---- K0: zero cnt0, cnt1, keptC0, dropCnt (contiguous 3*6400+1 ints) ----
__global__ void k_zero(int* __restrict__ z) {
    int i = blockIdx.x * 256 + threadIdx.x;
    if (i < 3 * NWIN + 1) z[i] = 0;
}

// ---- K1: window ids for both shifts + scatter into shift-0 segments ----
__global__ void __launch_bounds__(256) k_winscat(
    const int4* __restrict__ c4, int n,
    int* __restrict__ w0a, int* __restrict__ w1a,
    int* __restrict__ cnt0, int* __restrict__ seg0) {
    int i = blockIdx.x * 256 + threadIdx.x;
    if (i >= n) return;
    int4 c = c4[i];                                  // [b, z, y, x]
    int w0 = c.x * 1600 + (c.w / 12) * 40 + (c.z / 12);
    int w1 = c.x * 1600 + ((c.w + 6) / 12) * 40 + ((c.z + 6) / 12);
    w0a[i] = w0;
    w1a[i] = w1;
    int p = atomicAdd(&cnt0[w0], 1);
    if (p < CAP) seg0[w0 * CAP + p] = i;             // overflow -> serial path
}

// ---- K2: shift-0 rank/keep + optimistic rk0 + fused shift-1 hist+scatter ----
__global__ void __launch_bounds__(256) k_rank0(
    const int* __restrict__ cnt0, const int* __restrict__ seg0,
    const int* __restrict__ w0a, const int* __restrict__ w1a, int n,
    int* __restrict__ keep0, int* __restrict__ rk0,
    int* __restrict__ cnt1, int* __restrict__ seg1) {
    int w = blockIdx.x * 4 + (threadIdx.x >> 6);
    int lane = threadIdx.x & 63;
    int k = cnt0[w];
    if (k == 0) return;
    int target = targ_of(k);
    const int* s = seg0 + w * CAP;
    if (k <= 64) {
        int v = (lane < k) ? s[lane] : 0x7FFFFFFF;
        int r = 0;
        for (int j = 0; j < k; j++) { int b = __shfl(v, j, 64); r += (b < v) ? 1 : 0; }
        if (lane < k) {
            int kp = (r < target) ? 1 : 0;
            keep0[v] = kp;
            if (kp) {
                rk0[v] = r;                          // rank among keep0 == r
                int w1 = w1a[v];
                int p = atomicAdd(&cnt1[w1], 1);
                if (p < CAP) seg1[w1 * CAP + p] = v;
            }
        }
    } else if (k <= CAP) {
        int k2 = k - 64;
        int v0 = s[lane];
        int v1 = (lane < k2) ? s[64 + lane] : 0x7FFFFFFF;
        int r0 = 0, r1 = 0;
        for (int j = 0; j < 64; j++) { int b = __shfl(v0, j, 64); r0 += (b < v0); r1 += (b < v1); }
        for (int j = 0; j < k2; j++) { int b = __shfl(v1, j, 64); r0 += (b < v0); r1 += (b < v1); }
        {
            int kp = (r0 < target) ? 1 : 0;
            keep0[v0] = kp;
            if (kp) {
                rk0[v0] = r0;
                int w1 = w1a[v0]; int p = atomicAdd(&cnt1[w1], 1);
                if (p < CAP) seg1[w1 * CAP + p] = v0;
            }
        }
        if (lane < k2) {
            int kp = (r1 < target) ? 1 : 0;
            keep0[v1] = kp;
            if (kp) {
                rk0[v1] = r1;
                int w1 = w1a[v1]; int p = atomicAdd(&cnt1[w1], 1);
                if (p < CAP) seg1[w1 * CAP + p] = v1;
            }
        }
    } else {
        // correctness fallback (statistically never): serial in-order scan
        if (lane == 0) {
            int c = 0;
            for (int i = 0; i < n; i++) {
                if (w0a[i] == w) {
                    int kp = (c < target) ? 1 : 0;
                    keep0[i] = kp;
                    if (kp) {
                        rk0[i] = c;
                        int w1 = w1a[i]; int p = atomicAdd(&cnt1[w1], 1);
                        if (p < CAP) seg1[w1 * CAP + p] = i;
                    }
                    c++;
                }
            }
        }
    }
}

// ---- K3: shift-1 rank -> keepF, rk1, keptC1, keptC0 atomics, droplist ----
__global__ void __launch_bounds__(256) k_rank1(
    const int* __restrict__ cnt1, const int* __restrict__ seg1,
    const int* __restrict__ w0a, const int* __restrict__ w1a,
    const int* __restrict__ keep0, int n,
    int* __restrict__ keepF, int* __restrict__ rk1,
    int* __restrict__ keptC1, int* __restrict__ keptC0,
    int* __restrict__ dropCnt, int* __restrict__ droplist) {
    int w = blockIdx.x * 4 + (threadIdx.x >> 6);
    int lane = threadIdx.x & 63;
    int k = cnt1[w];
    int target = targ_of(k);
    if (lane == 0) keptC1[w] = (k < target) ? k : target;   // prefix property
    if (k == 0) return;
    const int* s = seg1 + w * CAP;
    if (k <= 64) {
        int v = (lane < k) ? s[lane] : 0x7FFFFFFF;
        int r = 0;
        for (int j = 0; j < k; j++) { int b = __shfl(v, j, 64); r += (b < v) ? 1 : 0; }
        if (lane < k) {
            int kp = (r < target) ? 1 : 0;
            keepF[v] = kp;
            if (kp) { rk1[v] = r; atomicAdd(&keptC0[w0a[v]], 1); }
            else    { int d = atomicAdd(dropCnt, 1); droplist[d] = v; }
        }
    } else if (k <= CAP) {
        int k2 = k - 64;
        int v0 = s[lane];
        int v1 = (lane < k2) ? s[64 + lane] : 0x7FFFFFFF;
        int r0 = 0, r1 = 0;
        for (int j = 0; j < 64; j++) { int b = __shfl(v0, j, 64); r0 += (b < v0); r1 += (b < v1); }
        for (int j = 0; j < k2; j++) { int b = __shfl(v1, j, 64); r0 += (b < v0); r1 += (b < v1); }
        {
            int kp = (r0 < target) ? 1 : 0;
            keepF[v0] = kp;
            if (kp) { rk1[v0] = r0; atomicAdd(&keptC0[w0a[v0]], 1); }
            else    { int d = atomicAdd(dropCnt, 1); droplist[d] = v0; }
        }
        if (lane < k2) {
            int kp = (r1 < target) ? 1 : 0;
            keepF[v1] = kp;
            if (kp) { rk1[v1] = r1; atomicAdd(&keptC0[w0a[v1]], 1); }
            else    { int d = atomicAdd(dropCnt, 1); droplist[d] = v1; }
        }
    } else {
        if (lane == 0) {
            int c = 0;
            for (int i = 0; i < n; i++) {
                if (w1a[i] == w && keep0[i]) {
                    int kp = (c < target) ? 1 : 0;
                    keepF[i] = kp;
                    if (kp) { rk1[i] = c; atomicAdd(&keptC0[w0a[i]], 1); }
                    else    { int d = atomicAdd(dropCnt, 1); droplist[d] = i; }
                    c++;
                }
            }
        }
    }
}

// ---- K4: conti scans (blocks 0,1) + sparse rk0 fixup from droplist ----
__device__ __forceinline__ void conti_scan(
    const int* __restrict__ cnt, const int* __restrict__ keptC,
    int* __restrict__ conti, int* pc0, int* pc1, int* pc2) {
    int t = threadIdx.x;
    int st = t * 25;                                  // 256 * 25 = 6400
    int c0 = 0, c1 = 0, c2 = 0;
    for (int j = 0; j < 25; j++) {
        int w = st + j;
        if (keptC[w] > 0) {
            int l = lvl_of(cnt[w]);
            c0 += (l == 0); c1 += (l == 1); c2 += (l == 2);
        }
    }
    pc0[t] = c0; pc1[t] = c1; pc2[t] = c2;
    __syncthreads();
    if (t == 0) {
        int a = 0, b = 0, c = 0;
        for (int j = 0; j < 256; j++) {
            int v0 = pc0[j], v1 = pc1[j], v2 = pc2[j];
            pc0[j] = a; pc1[j] = b; pc2[j] = c;
            a += v0; b += v1; c += v2;
        }
    }
    __syncthreads();
    int a0 = pc0[t], a1 = pc1[t], a2 = pc2[t];
    for (int j = 0; j < 25; j++) {
        int w = st + j;
        int l = lvl_of(cnt[w]);
        conti[w] = (l == 0) ? a0 : (l == 1) ? a1 : (l == 2) ? a2 : 0;
        if (keptC[w] > 0) {
            if (l == 0) a0++; else if (l == 1) a1++; else if (l == 2) a2++;
        }
    }
}

__global__ void k_fix(
    const int* __restrict__ cnt0, const int* __restrict__ keptC0, int* __restrict__ conti0,
    const int* __restrict__ cnt1, const int* __restrict__ keptC1, int* __restrict__ conti1,
    const int* __restrict__ dropCnt, const int* __restrict__ droplist,
    const int* __restrict__ w0a, const int* __restrict__ seg0,
    const int* __restrict__ keep0, const int* __restrict__ keepF,
    int* __restrict__ rk0, int n) {
    __shared__ int pc0[256], pc1[256], pc2[256];
    if (blockIdx.x == 0) { conti_scan(cnt0, keptC0, conti0, pc0, pc1, pc2); return; }
    if (blockIdx.x == 1) { conti_scan(cnt1, keptC1, conti1, pc0, pc1, pc2); return; }
    // droplist apply: one wave per dropped survivor (statistically none)
    int nd = *dropCnt;
    if (nd == 0) return;
    int waveId = (blockIdx.x - 2) * 4 + (threadIdx.x >> 6);
    int nWaves = (gridDim.x - 2) * 4;
    int lane = threadIdx.x & 63;
    for (int e = waveId; e < nd; e += nWaves) {
        int u = droplist[e];
        int w = w0a[u];
        int k = cnt0[w];
        if (k <= CAP) {
            const int* s = seg0 + w * CAP;
            for (int j = lane; j < k; j += 64) {
                int v = s[j];
                if (v > u && keep0[v] && keepF[v]) atomicSub(&rk0[v], 1);
            }
        } else if (lane == 0) {                       // double-rare fallback
            for (int i = u + 1; i < n; i++) {
                if (w0a[i] == w && keep0[i] && keepF[i]) atomicSub(&rk0[i], 1);
            }
        }
    }
}

// ---- K5: per-voxel scalar outputs + masked feature copy (block-split) ----
__global__ void __launch_bounds__(256) k_finalfeat(
    int n, const int* __restrict__ w0a, const int* __restrict__ w1a,
    const int* __restrict__ keep0, const int* __restrict__ keepF,
    const int* __restrict__ cnt0, const int* __restrict__ cnt1,
    const int* __restrict__ conti0, const int* __restrict__ conti1,
    const int* __restrict__ rk0, const int* __restrict__ rk1,
    const float4* __restrict__ feat, float* __restrict__ out, int nbScalar) {
    if ((int)blockIdx.x < nbScalar) {
        int i = blockIdx.x * 256 + threadIdx.x;
        if (i >= n) return;
        size_t N = (size_t)n;
        float* o = out + N * 128;                     // after feat block
        int w0 = w0a[i], w1 = w1a[i];
        int k0 = keep0[i];
        int kf = (k0 && keepF[i]) ? 1 : 0;
        int l0 = lvl_of(cnt0[w0]);
        int l1 = k0 ? lvl_of(cnt1[w1]) : -1;
        int f0 = -1, f1 = -1;
        if (kf) {
            int mt0 = (l0 == 0) ? 30 : (l0 == 1) ? 60 : 100;
            int mt1 = (l1 == 0) ? 30 : (l1 == 1) ? 60 : 100;
            f0 = conti0[w0] * mt0 + rk0[i];
            f1 = conti1[w1] * mt1 + rk1[i];
        }
        o[i]         = (float)kf;   // keep
        o[N + i]     = (float)l0;   // lvl0
        o[2 * N + i] = (float)l1;   // lvl1
        o[3 * N + i] = (float)w0;   // bwi0
        o[4 * N + i] = (float)w1;   // bwi1
        o[5 * N + i] = (float)f0;   // f2w0
        o[6 * N + i] = (float)f1;   // f2w1
    } else {
        int gid = (blockIdx.x - nbScalar) * 256 + threadIdx.x;
        int total = n * 32;                           // 128 floats = 32 float4/row
        if (gid >= total) return;
        int row = gid >> 5;
        float4 v = feat[gid];
        if (!(keep0[row] && keepF[row])) { v.x = 0.f; v.y = 0.f; v.z = 0.f; v.w = 0.f; }
        ((float4*)out)[gid] = v;
    }
}

extern "C" void kernel_launch(void* const* d_in, const int* in_sizes, int n_in,
                              void* d_out, int out_size, void* d_ws, size_t ws_size,
                              hipStream_t stream) {
    (void)n_in; (void)out_size; (void)ws_size;
    const float* feat = (const float*)d_in[0];
    const int* coors  = (const int*)d_in[1];
    int n = in_sizes[1] / 4;           // coors is [N,4]
    float* out = (float*)d_out;
    int* ws = (int*)d_ws;

    // workspace layout (ints): 44800 + 7n + 2*NWIN*CAP ~= 15.2 MB at N=300000
    int* cnt0     = ws;                // zeroed
    int* cnt1     = ws + 6400;         // zeroed
    int* keptC0   = ws + 12800;        // zeroed
    int* dropCnt  = ws + 19200;        // zeroed (1 int)
    int* keptC1   = ws + 25600;
    int* conti0   = ws + 32000;
    int* conti1   = ws + 38400;
    int* droplist = ws + 44800;        // n ints (worst case)
    int* w0a      = droplist + n;
    int* w1a      = w0a + n;
    int* keep0    = w1a + n;
    int* keepF    = keep0 + n;
    int* rk0      = keepF + n;
    int* rk1      = rk0 + n;
    int* seg0     = rk1 + n;
    int* seg1     = seg0 + NWIN * CAP;

    int nb = (n + 255) / 256;
    int fb = (n * 32 + 255) / 256;

    k_zero<<<(3 * NWIN + 1 + 255) / 256, 256, 0, stream>>>(cnt0);
    k_winscat<<<nb, 256, 0, stream>>>((const int4*)coors, n, w0a, w1a, cnt0, seg0);
    k_rank0<<<NWIN / 4, 256, 0, stream>>>(cnt0, seg0, w0a, w1a, n,
                                          keep0, rk0, cnt1, seg1);
    k_rank1<<<NWIN / 4, 256, 0, stream>>>(cnt1, seg1, w0a, w1a, keep0, n,
                                          keepF, rk1, keptC1, keptC0,
                                          dropCnt, droplist);
    k_fix<<<66, 256, 0, stream>>>(cnt0, keptC0, conti0, cnt1, keptC1, conti1,
                                  dropCnt, droplist, w0a, seg0, keep0, keepF,
                                  rk0, n);
    k_finalfeat<<<nb + fb, 256, 0, stream>>>(n, w0a, w1a, keep0, keepF, cnt0, cnt1,
                                             conti0, conti1, rk0, rk1,
                                             (const float4*)feat, out, nb);
}